// Round 8
// baseline (316.552 us; speedup 1.0000x reference)
//
#include <hip/hip_runtime.h>
#include <math.h>

namespace {

constexpr int B  = 16;
constexpr int S  = 1024;
constexpr int H  = 768;
constexpr int NH = 12;
constexpr int DH = 64;
constexpr int FF = 3072;
constexpr float EPS = 1e-12f;

__device__ __forceinline__ float waveReduceSum(float v) {
#pragma unroll
    for (int d = 1; d < 64; d <<= 1) v += __shfl_xor(v, d);
    return v;
}

// 256-thread block reduce; red = 4 floats of shared
__device__ __forceinline__ float blockReduce256(float v, float* red) {
    const int lane = threadIdx.x & 63, wid = threadIdx.x >> 6;
    v = waveReduceSum(v);
    __syncthreads();
    if (lane == 0) red[wid] = v;
    __syncthreads();
    return red[0] + red[1] + red[2] + red[3];
}

// Take a finish-ticket; returns batch id [0,16) if this block is one of the
// last 16 finishers (after spinning until ALL blocks are done), else -1.
__device__ __forceinline__ int lastBlocksTicket(unsigned* counter, unsigned total) {
    __shared__ unsigned tick_sh;
    __threadfence();                        // release partial writes
    if (threadIdx.x == 0) tick_sh = atomicAdd(counter, 1u);
    __syncthreads();
    const unsigned ticket = tick_sh;
    if (ticket < total - 16) return -1;
    if (threadIdx.x == 0) {
        while (atomicAdd(counter, 0u) < total) __builtin_amdgcn_s_sleep(8);
    }
    __syncthreads();
    __threadfence();                        // acquire others' writes
    return (int)(ticket - (total - 16));
}

// ---------------------------------------------------------------------------
// split-K partial GEMM over the 16 CLS rows:
//   part[sp][b][j] = sum_{i in split sp} A[b,i] * W[i,j]
// grid (N/64, ISPL), block 256 = 64 j-lanes x 4 b-groups
// ---------------------------------------------------------------------------
template <int K, int ISPL, int N>
__global__ __launch_bounds__(256) void gemm_partial(
        const float* __restrict__ A, int lda,
        const float* __restrict__ W, float* __restrict__ part,
        unsigned* __restrict__ counters) {
    constexpr int IR = K / ISPL;
    __shared__ float Asl[B * IR];
    const int jt  = blockIdx.x;
    const int sp  = blockIdx.y;
    const int i0  = sp * IR;
    const int tid = threadIdx.x;

    if (counters && jt == 0 && sp == 0 && tid < 8) counters[tid] = 0;

    for (int e = tid; e < B * IR; e += 256) {
        const int b = e / IR, ii = e % IR;
        Asl[e] = A[(size_t)b * lda + i0 + ii];
    }
    __syncthreads();

    const int jl = tid & 63;
    const int bg = tid >> 6;
    const int j  = jt * 64 + jl;
    const float* wp_ = W + (size_t)i0 * N + j;
    float acc0 = 0.f, acc1 = 0.f, acc2 = 0.f, acc3 = 0.f;
#pragma unroll
    for (int ii = 0; ii < IR; ++ii) {
        const float w = wp_[(size_t)ii * N];
        acc0 += w * Asl[(bg * 4 + 0) * IR + ii];
        acc1 += w * Asl[(bg * 4 + 1) * IR + ii];
        acc2 += w * Asl[(bg * 4 + 2) * IR + ii];
        acc3 += w * Asl[(bg * 4 + 3) * IR + ii];
    }
    float* pp = part + ((size_t)sp * B) * N + j;
    pp[(size_t)(bg * 4 + 0) * N] = acc0;
    pp[(size_t)(bg * 4 + 1) * N] = acc1;
    pp[(size_t)(bg * 4 + 2) * N] = acc2;
    pp[(size_t)(bg * 4 + 3) * N] = acc3;
}

// wo GEMM (A = bias + sum of RED input partials) + fused LN1 tail:
// last 16 blocks each do one batch's LayerNorm(sum part + bo + x_row0) -> out
template <int ISPL, int RED>
__global__ __launch_bounds__(256) void gemm_wo_ln(
        const float* __restrict__ Ain, const float* __restrict__ biasA,
        const float* __restrict__ W, float* __restrict__ part,
        const float* __restrict__ bo, const float* __restrict__ x,
        const float* __restrict__ g, const float* __restrict__ bet,
        float* __restrict__ out, unsigned* __restrict__ counter) {
    constexpr int IR = H / ISPL;
    __shared__ float Asl[B * IR];
    __shared__ float red[4];
    const int jt  = blockIdx.x;
    const int sp  = blockIdx.y;
    const int i0  = sp * IR;
    const int tid = threadIdx.x;

    for (int e = tid; e < B * IR; e += 256) {
        const int b = e / IR, ii = e % IR;
        float v = biasA[i0 + ii];
#pragma unroll
        for (int sp2 = 0; sp2 < RED; ++sp2)
            v += Ain[((size_t)sp2 * B + b) * H + i0 + ii];
        Asl[e] = v;
    }
    __syncthreads();

    const int jl = tid & 63;
    const int bg = tid >> 6;
    const int j  = jt * 64 + jl;
    const float* wp_ = W + (size_t)i0 * H + j;
    float acc0 = 0.f, acc1 = 0.f, acc2 = 0.f, acc3 = 0.f;
#pragma unroll
    for (int ii = 0; ii < IR; ++ii) {
        const float w = wp_[(size_t)ii * H];
        acc0 += w * Asl[(bg * 4 + 0) * IR + ii];
        acc1 += w * Asl[(bg * 4 + 1) * IR + ii];
        acc2 += w * Asl[(bg * 4 + 2) * IR + ii];
        acc3 += w * Asl[(bg * 4 + 3) * IR + ii];
    }
    float* pp = part + ((size_t)sp * B) * H + j;
    pp[(size_t)(bg * 4 + 0) * H] = acc0;
    pp[(size_t)(bg * 4 + 1) * H] = acc1;
    pp[(size_t)(bg * 4 + 2) * H] = acc2;
    pp[(size_t)(bg * 4 + 3) * H] = acc3;

    const int b = lastBlocksTicket(counter, gridDim.x * gridDim.y);
    if (b < 0) return;
    float v[3];
#pragma unroll
    for (int c = 0; c < 3; ++c) {
        const int jj = tid + 256 * c;
        float t = bo[jj] + x[(size_t)b * S * H + jj];
#pragma unroll
        for (int sp2 = 0; sp2 < ISPL; ++sp2)
            t += part[((size_t)sp2 * B + b) * H + jj];
        v[c] = t;
    }
    const float mu = blockReduce256(v[0] + v[1] + v[2], red) * (1.0f / H);
    const float d0 = v[0] - mu, d1 = v[1] - mu, d2 = v[2] - mu;
    const float var = blockReduce256(d0 * d0 + d1 * d1 + d2 * d2, red) * (1.0f / H);
    const float rs = rsqrtf(var + EPS);
#pragma unroll
    for (int c = 0; c < 3; ++c) {
        const int jj = tid + 256 * c;
        out[(size_t)b * H + jj] = (v[c] - mu) * rs * g[jj] + bet[jj];
    }
}

// ffn2 GEMM (gelu in staging) + fused LN2 tail (resid = attn_out)
template <int ISPL, int RED>
__global__ __launch_bounds__(256) void gemm_ffn2_ln(
        const float* __restrict__ Ain, const float* __restrict__ b1,
        const float* __restrict__ W, float* __restrict__ part,
        const float* __restrict__ b2, const float* __restrict__ resid,
        const float* __restrict__ g, const float* __restrict__ bet,
        float* __restrict__ out, unsigned* __restrict__ counter) {
    constexpr int IR = FF / ISPL;
    __shared__ float Asl[B * IR];
    __shared__ float red[4];
    const int jt  = blockIdx.x;
    const int sp  = blockIdx.y;
    const int i0  = sp * IR;
    const int tid = threadIdx.x;

    for (int e = tid; e < B * IR; e += 256) {
        const int b = e / IR, ii = e % IR;
        float v = b1[i0 + ii];
#pragma unroll
        for (int sp2 = 0; sp2 < RED; ++sp2)
            v += Ain[((size_t)sp2 * B + b) * FF + i0 + ii];
        Asl[e] = 0.5f * v * (1.0f + erff(v * 0.70710678118654752440f));
    }
    __syncthreads();

    const int jl = tid & 63;
    const int bg = tid >> 6;
    const int j  = jt * 64 + jl;
    const float* wp_ = W + (size_t)i0 * H + j;
    float acc0 = 0.f, acc1 = 0.f, acc2 = 0.f, acc3 = 0.f;
#pragma unroll
    for (int ii = 0; ii < IR; ++ii) {
        const float w = wp_[(size_t)ii * H];
        acc0 += w * Asl[(bg * 4 + 0) * IR + ii];
        acc1 += w * Asl[(bg * 4 + 1) * IR + ii];
        acc2 += w * Asl[(bg * 4 + 2) * IR + ii];
        acc3 += w * Asl[(bg * 4 + 3) * IR + ii];
    }
    float* pp = part + ((size_t)sp * B) * H + j;
    pp[(size_t)(bg * 4 + 0) * H] = acc0;
    pp[(size_t)(bg * 4 + 1) * H] = acc1;
    pp[(size_t)(bg * 4 + 2) * H] = acc2;
    pp[(size_t)(bg * 4 + 3) * H] = acc3;

    const int b = lastBlocksTicket(counter, gridDim.x * gridDim.y);
    if (b < 0) return;
    float v[3];
#pragma unroll
    for (int c = 0; c < 3; ++c) {
        const int jj = tid + 256 * c;
        float t = b2[jj] + resid[(size_t)b * H + jj];
#pragma unroll
        for (int sp2 = 0; sp2 < ISPL; ++sp2)
            t += part[((size_t)sp2 * B + b) * H + jj];
        v[c] = t;
    }
    const float mu = blockReduce256(v[0] + v[1] + v[2], red) * (1.0f / H);
    const float d0 = v[0] - mu, d1 = v[1] - mu, d2 = v[2] - mu;
    const float var = blockReduce256(d0 * d0 + d1 * d1 + d2 * d2, red) * (1.0f / H);
    const float rs = rsqrtf(var + EPS);
#pragma unroll
    for (int c = 0; c < 3; ++c) {
        const int jj = tid + 256 * c;
        out[(size_t)b * H + jj] = (v[c] - mu) * rs * g[jj] + bet[jj];
    }
}

// pool GEMM + fused classifier tail
template <int ISPL>
__global__ __launch_bounds__(256) void gemm_pool_cls(
        const float* __restrict__ A, const float* __restrict__ W,
        float* __restrict__ part,
        const float* __restrict__ bp, const float* __restrict__ wm,
        const float* __restrict__ bm, float* __restrict__ out,
        unsigned* __restrict__ counter) {
    constexpr int IR = H / ISPL;
    __shared__ float Asl[B * IR];
    __shared__ float red[4];
    const int jt  = blockIdx.x;
    const int sp  = blockIdx.y;
    const int i0  = sp * IR;
    const int tid = threadIdx.x;

    for (int e = tid; e < B * IR; e += 256) {
        const int b = e / IR, ii = e % IR;
        Asl[e] = A[(size_t)b * H + i0 + ii];
    }
    __syncthreads();

    const int jl = tid & 63;
    const int bg = tid >> 6;
    const int j  = jt * 64 + jl;
    const float* wp_ = W + (size_t)i0 * H + j;
    float acc0 = 0.f, acc1 = 0.f, acc2 = 0.f, acc3 = 0.f;
#pragma unroll
    for (int ii = 0; ii < IR; ++ii) {
        const float w = wp_[(size_t)ii * H];
        acc0 += w * Asl[(bg * 4 + 0) * IR + ii];
        acc1 += w * Asl[(bg * 4 + 1) * IR + ii];
        acc2 += w * Asl[(bg * 4 + 2) * IR + ii];
        acc3 += w * Asl[(bg * 4 + 3) * IR + ii];
    }
    float* pp = part + ((size_t)sp * B) * H + j;
    pp[(size_t)(bg * 4 + 0) * H] = acc0;
    pp[(size_t)(bg * 4 + 1) * H] = acc1;
    pp[(size_t)(bg * 4 + 2) * H] = acc2;
    pp[(size_t)(bg * 4 + 3) * H] = acc3;

    const int b = lastBlocksTicket(counter, gridDim.x * gridDim.y);
    if (b < 0) return;
    float s = 0.f;
#pragma unroll
    for (int c = 0; c < 3; ++c) {
        const int jj = tid + 256 * c;
        float t = bp[jj];
#pragma unroll
        for (int sp2 = 0; sp2 < ISPL; ++sp2)
            t += part[((size_t)sp2 * B + b) * H + jj];
        s += tanhf(t) * wm[jj];
    }
    s = blockReduce256(s, red);
    if (tid == 0) out[b] = s + bm[0];
}

// u[b,h,i] = sum_d wk[i, h*64+d] * (q0 reduced); constk[b,h] = bk_h . q0_h
__global__ __launch_bounds__(256) void u_kernel(
        const float* __restrict__ q0_part, const float* __restrict__ bq,
        const float* __restrict__ wk, const float* __restrict__ bk,
        float* __restrict__ u, float* __restrict__ constk) {
    const int b = blockIdx.x / NH, h = blockIdx.x % NH;
    __shared__ __align__(16) float qh[DH];
    const int tid = threadIdx.x;
    if (tid < DH) {
        float v = bq[h * DH + tid];
#pragma unroll
        for (int sp = 0; sp < 24; ++sp)
            v += q0_part[((size_t)sp * B + b) * H + h * DH + tid];
        qh[tid] = v;
    }
    __syncthreads();
    if (tid < DH) {
        float v = bk[h * DH + tid] * qh[tid];
        v = waveReduceSum(v);
        if (tid == 0) constk[b * NH + h] = v;
    }
    const int jj = tid & 3, iq = tid >> 2;
    const float4* qv = (const float4*)qh;
    float4 q4[4];
#pragma unroll
    for (int c = 0; c < 4; ++c) q4[c] = qv[jj * 4 + c];
#pragma unroll 4
    for (int ir = 0; ir < 12; ++ir) {
        const int i = ir * 64 + iq;
        const float4* wr = (const float4*)(wk + (size_t)i * H + h * DH);
        float s = 0.f;
#pragma unroll
        for (int c = 0; c < 4; ++c) {
            const float4 w = wr[jj * 4 + c];
            s += w.x * q4[c].x + w.y * q4[c].y + w.z * q4[c].z + w.w * q4[c].w;
        }
        s += __shfl_xor(s, 1);
        s += __shfl_xor(s, 2);
        if (jj == 0) u[((size_t)(b * NH + h)) * H + i] = s;
    }
}

// ===== fused score(exp) + psum + unnormalized xbar partial (16 slots) =======
// grid (B, 16), block 256; block handles k-tiles kt0 and kt0+16, accumulates
// the xbar partial in registers across both -> xpart[(b*16+kt0)][h][:]
__global__ __launch_bounds__(256, 2) void score_xbar(
        const float* __restrict__ x, const float* __restrict__ u,
        const float* __restrict__ constk, const float* __restrict__ mask,
        float* __restrict__ psum, float* __restrict__ xpart) {
    const int b   = blockIdx.x;
    const int kt0 = blockIdx.y;
    __shared__ __align__(16) float ul[NH * H];   // 9216
    __shared__ float e_sh[32 * NH];              // 384
    __shared__ float ck[NH];
    __shared__ float wsum[4][NH];
    const int tid = threadIdx.x;
    {
        const float4* ug = (const float4*)(u + (size_t)b * NH * H);
        float4* ul4 = (float4*)ul;
        for (int e = tid; e < NH * H / 4; e += 256) ul4[e] = ug[e];
        if (tid < NH) ck[tid] = constk[b * NH + tid];
    }
    float aB0[NH], aB1[NH], aB2[NH];
#pragma unroll
    for (int h = 0; h < NH; ++h) { aB0[h] = 0.f; aB1[h] = 0.f; aB2[h] = 0.f; }
    const int jj = tid & 15, kk = tid >> 4;
    const float4* ul4 = (const float4*)ul;

    for (int it = 0; it < 2; ++it) {
        const int kt = kt0 + it * 16;
        __syncthreads();   // it0: ul ready; it1: e_sh/wsum WAR protection
        const int k0 = kt * 32 + kk * 2;
        float4 xv0[12], xv1[12];
        {
            const float4* xr0 = (const float4*)(x + ((size_t)b * S + k0) * H);
            const float4* xr1 = (const float4*)(x + ((size_t)b * S + k0 + 1) * H);
#pragma unroll
            for (int t = 0; t < 12; ++t) { xv0[t] = xr0[jj + 16 * t]; xv1[t] = xr1[jj + 16 * t]; }
        }
        float acc0[NH], acc1[NH];
#pragma unroll
        for (int h = 0; h < NH; ++h) {
            float a0 = 0.f, a1 = 0.f;
#pragma unroll
            for (int t = 0; t < 12; ++t) {
                const float4 uv = ul4[h * 192 + jj + 16 * t];
                a0 += xv0[t].x * uv.x + xv0[t].y * uv.y + xv0[t].z * uv.z + xv0[t].w * uv.w;
                a1 += xv1[t].x * uv.x + xv1[t].y * uv.y + xv1[t].z * uv.z + xv1[t].w * uv.w;
            }
            acc0[h] = a0; acc1[h] = a1;
        }
#pragma unroll
        for (int h = 0; h < NH; ++h) {
#pragma unroll
            for (int d = 1; d < 16; d <<= 1) {
                acc0[h] += __shfl_xor(acc0[h], d);
                acc1[h] += __shfl_xor(acc1[h], d);
            }
        }
        const float mk0 = mask[b * S + k0];
        const float mk1 = mask[b * S + k0 + 1];
        float e0[NH], e1[NH], ps[NH];
#pragma unroll
        for (int h = 0; h < NH; ++h) {
            e0[h] = expf(acc0[h] * 0.125f + ck[h] + mk0);
            e1[h] = expf(acc1[h] * 0.125f + ck[h] + mk1);
            ps[h] = e0[h] + e1[h];
        }
        if (jj == 0) {
#pragma unroll
            for (int h = 0; h < NH; ++h) {
                e_sh[(kk * 2) * NH + h]     = e0[h];
                e_sh[(kk * 2 + 1) * NH + h] = e1[h];
            }
        }
#pragma unroll
        for (int h = 0; h < NH; ++h) {
            ps[h] += __shfl_xor(ps[h], 16);
            ps[h] += __shfl_xor(ps[h], 32);
        }
        const int wid = tid >> 6;
        if ((tid & 63) == 0) {
#pragma unroll
            for (int h = 0; h < NH; ++h) wsum[wid][h] = ps[h];
        }
        __syncthreads();
        if (tid < NH)
            psum[((size_t)(b * 32 + kt)) * NH + tid] =
                wsum[0][tid] + wsum[1][tid] + wsum[2][tid] + wsum[3][tid];

        // accumulate unnormalized xbar partial; x rows are cache-hot
        const float* xr = x + ((size_t)b * S + kt * 32) * H;
#pragma unroll 2
        for (int k = 0; k < 32; ++k) {
            const float x0 = xr[(size_t)k * H + tid];
            const float x1 = xr[(size_t)k * H + tid + 256];
            const float x2 = xr[(size_t)k * H + tid + 512];
#pragma unroll
            for (int h = 0; h < NH; ++h) {
                const float ev = e_sh[k * NH + h];
                aB0[h] += ev * x0; aB1[h] += ev * x1; aB2[h] += ev * x2;
            }
        }
    }
    float* op = xpart + ((size_t)(b * 16 + kt0)) * NH * H;
#pragma unroll
    for (int h = 0; h < NH; ++h) {
        op[(size_t)h * H + tid]       = aB0[h];
        op[(size_t)h * H + tid + 256] = aB1[h];
        op[(size_t)h * H + tid + 512] = aB2[h];
    }
}

// ===== ctx_part[sp][b][head*64+jl] = ((sum_16 xpart)*rinv) @ wv_head ========
template <int ISPL>
__global__ __launch_bounds__(256) void gemm_xpart(
        const float* __restrict__ xpart, const float* __restrict__ psum,
        const float* __restrict__ W, float* __restrict__ part) {
    constexpr int IR = H / ISPL;
    __shared__ float Asl[B * IR];
    __shared__ float rinv[B];
    const int jt  = blockIdx.x;       // head
    const int sp  = blockIdx.y;
    const int i0  = sp * IR;
    const int tid = threadIdx.x;

    if (tid < B) {
        float s = 0.f;
#pragma unroll
        for (int kt = 0; kt < 32; ++kt)
            s += psum[((size_t)(tid * 32 + kt)) * NH + jt];
        rinv[tid] = 1.0f / s;
    }
    for (int e = tid; e < B * IR; e += 256) {
        const int b = e / IR, ii = e % IR;
        float v = 0.f;
#pragma unroll
        for (int s2 = 0; s2 < 16; ++s2)
            v += xpart[((size_t)(b * 16 + s2)) * NH * H + (size_t)jt * H + i0 + ii];
        Asl[e] = v;
    }
    __syncthreads();

    const int jl = tid & 63, bg = tid >> 6;
    const int j = jt * 64 + jl;
    const float* wp_ = W + (size_t)i0 * H + j;
    float a0 = 0, a1 = 0, a2 = 0, a3 = 0;
#pragma unroll
    for (int ii = 0; ii < IR; ++ii) {
        const float w = wp_[(size_t)ii * H];
        a0 += w * Asl[(bg * 4 + 0) * IR + ii];
        a1 += w * Asl[(bg * 4 + 1) * IR + ii];
        a2 += w * Asl[(bg * 4 + 2) * IR + ii];
        a3 += w * Asl[(bg * 4 + 3) * IR + ii];
    }
    float* pp = part + ((size_t)sp * B) * H + j;
    pp[(size_t)(bg * 4 + 0) * H] = a0 * rinv[bg * 4 + 0];
    pp[(size_t)(bg * 4 + 1) * H] = a1 * rinv[bg * 4 + 1];
    pp[(size_t)(bg * 4 + 2) * H] = a2 * rinv[bg * 4 + 2];
    pp[(size_t)(bg * 4 + 3) * H] = a3 * rinv[bg * 4 + 3];
}

// FFN1: plain split-K partial GEMM (no counter init)
template <int ISPL>
__global__ __launch_bounds__(256) void gemm_ffn1(
        const float* __restrict__ A,
        const float* __restrict__ W, float* __restrict__ part) {
    constexpr int IR = H / ISPL;
    __shared__ float Asl[B * IR];
    const int jt  = blockIdx.x;
    const int sp  = blockIdx.y;
    const int i0  = sp * IR;
    const int tid = threadIdx.x;

    for (int e = tid; e < B * IR; e += 256) {
        const int b = e / IR, ii = e % IR;
        Asl[e] = A[(size_t)b * H + i0 + ii];
    }
    __syncthreads();

    const int jl = tid & 63;
    const int bg = tid >> 6;
    const int j  = jt * 64 + jl;
    const float* wp_ = W + (size_t)i0 * FF + j;
    float acc0 = 0.f, acc1 = 0.f, acc2 = 0.f, acc3 = 0.f;
#pragma unroll
    for (int ii = 0; ii < IR; ++ii) {
        const float w = wp_[(size_t)ii * FF];
        acc0 += w * Asl[(bg * 4 + 0) * IR + ii];
        acc1 += w * Asl[(bg * 4 + 1) * IR + ii];
        acc2 += w * Asl[(bg * 4 + 2) * IR + ii];
        acc3 += w * Asl[(bg * 4 + 3) * IR + ii];
    }
    float* pp = part + ((size_t)sp * B) * FF + j;
    pp[(size_t)(bg * 4 + 0) * FF] = acc0;
    pp[(size_t)(bg * 4 + 1) * FF] = acc1;
    pp[(size_t)(bg * 4 + 2) * FF] = acc2;
    pp[(size_t)(bg * 4 + 3) * FF] = acc3;
}

} // namespace

extern "C" void kernel_launch(void* const* d_in, const int* in_sizes, int n_in,
                              void* d_out, int out_size, void* d_ws, size_t ws_size,
                              hipStream_t stream) {
    const float* x    = (const float*)d_in[0];
    const float* mask = (const float*)d_in[1];
    const float* wq   = (const float*)d_in[2];
    const float* bq   = (const float*)d_in[3];
    const float* wk   = (const float*)d_in[4];
    const float* bk   = (const float*)d_in[5];
    const float* wv   = (const float*)d_in[6];
    const float* bv   = (const float*)d_in[7];
    const float* wo   = (const float*)d_in[8];
    const float* bo   = (const float*)d_in[9];
    const float* ln1g = (const float*)d_in[10];
    const float* ln1b = (const float*)d_in[11];
    const float* w1   = (const float*)d_in[12];
    const float* b1   = (const float*)d_in[13];
    const float* w2   = (const float*)d_in[14];
    const float* b2   = (const float*)d_in[15];
    const float* ln2g = (const float*)d_in[16];
    const float* ln2b = (const float*)d_in[17];
    const float* wp   = (const float*)d_in[18];
    const float* bp   = (const float*)d_in[19];
    const float* wm   = (const float*)d_in[20];
    const float* bm   = (const float*)d_in[21];
    float* out = (float*)d_out;

    // -------- workspace, linear layout (~21 MB) -----------------------------
    float* ws = (float*)d_ws;
    size_t o = 0;
    unsigned* counters = (unsigned*)(ws); o += 64;            // 3 used, 0-init by k1
    float* u         = ws + o; o += (size_t)B * NH * H;       // 147456
    float* constk    = ws + o; o += 256;
    float* psum      = ws + o; o += (size_t)B * 32 * NH;      // 6144
    float* attn_out  = ws + o; o += (size_t)B * H;
    float* hidden    = ws + o; o += (size_t)B * H;
    float* xpart     = ws + o; o += (size_t)16 * B * NH * H;  // 2359296
    float* q0_part   = ws + o; o += (size_t)24 * B * H;       // 294912
    float* ctx_part  = ws + o; o += (size_t)24 * B * H;
    float* wo_part   = ws + o; o += (size_t)24 * B * H;
    float* ffn1_part = ws + o; o += (size_t)24 * B * FF;      // 1179648
    float* ffn2_part = ws + o; o += (size_t)48 * B * H;       // 589824
    float* pool_part = ws + o; o += (size_t)24 * B * H;
    (void)ws_size; (void)in_sizes; (void)n_in; (void)out_size;

    // 1) q0 partials = x[:,0,:] @ wq  (288 blocks; zeroes the ticket counters)
    gemm_partial<H, 24, H><<<dim3(12, 24), 256, 0, stream>>>(x, S * H, wq, q0_part, counters);

    // 2) u + constk  (192 blocks)
    u_kernel<<<B * NH, 256, 0, stream>>>(q0_part, bq, wk, bk, u, constk);

    // 3) scores->exp + psum + xbar partials, 16 slots  (256 blocks)
    score_xbar<<<dim3(B, 16), 256, 0, stream>>>(x, u, constk, mask, psum, xpart);

    // 4) ctx partials  (288 blocks)
    gemm_xpart<24><<<dim3(12, 24), 256, 0, stream>>>(xpart, psum, wv, ctx_part);

    // 5) wo GEMM + fused LN1 tail  (288 blocks; counter 0)
    gemm_wo_ln<24, 24><<<dim3(12, 24), 256, 0, stream>>>(
        ctx_part, bv, wo, wo_part, bo, x, ln1g, ln1b, attn_out, counters + 0);

    // 6) FFN1  (1152 blocks)
    gemm_ffn1<24><<<dim3(48, 24), 256, 0, stream>>>(attn_out, w1, ffn1_part);

    // 7) FFN2 (gelu staging) + fused LN2 tail  (576 blocks; counter 1)
    gemm_ffn2_ln<48, 24><<<dim3(12, 48), 256, 0, stream>>>(
        ffn1_part, b1, w2, ffn2_part, b2, attn_out, ln2g, ln2b, hidden, counters + 1);

    // 8) pool GEMM + fused classifier tail  (288 blocks; counter 2)
    gemm_pool_cls<24><<<dim3(12, 24), 256, 0, stream>>>(
        hidden, wp, pool_part, bp, wm, bm, out, counters + 2);
}